// Round 2
// baseline (85.147 us; speedup 1.0000x reference)
//
#include <hip/hip_runtime.h>

#define BTOT 4096
#define G 4              // batch items per block
#define NC 16
#define WIN 247
#define KTOT 250         // padded taps; W=0 for k in [247,250)
#define NW 10
#define NBLK (BTOT / G)  // 1024 blocks

// k-segments inside a block: ks0:[0,70) 7 chunks; ks1:[70,130), ks2:[130,190), ks3:[190,250) 6 chunks each.

__device__ __forceinline__ unsigned bf16rne(float f) {
    unsigned u = __float_as_uint(f);
    return (u + 0x7fffu + ((u >> 16) & 1u)) >> 16;
}

// One 10-step compute chunk. kbase: first tap index; lbase: first n-index to prefetch
// (data chunk kchunk+2); CUR/NXT: named register buffers (all indexing static after unroll).
#define CHUNK(kbase, lbase, CUR, NXT, DO_LOAD)                                  \
    _Pragma("unroll")                                                           \
    for (int j = 0; j < 10; ++j) {                                              \
        unsigned wp = WL[((kbase) + j) * NC + c];                               \
        float wr = __uint_as_float(wp << 16);                                   \
        float wi = __uint_as_float(wp & 0xffff0000u);                           \
        _Pragma("unroll")                                                       \
        for (int w = 0; w < 10; ++w) {                                          \
            int idx = j + w;                                                    \
            float2 v = (idx < 10) ? CUR[idx] : NXT[idx - 10];                   \
            accr[w] = fmaf(v.x, wr, accr[w]);                                   \
            acci[w] = fmaf(v.y, wi, acci[w]);                                   \
        }                                                                       \
        if (DO_LOAD) {                                                          \
            int n = (lbase) + j;                                                \
            n = (n < 255) ? n : 255;                                            \
            CUR[j] = xp[n * 16];                                                \
        }                                                                       \
    }

__global__ __launch_bounds__(256) void k_main(
    const float* __restrict__ x,
    const float* __restrict__ Wr, const float* __restrict__ Wi,
    const float* __restrict__ Wnl, const float* __restrict__ Wc,
    const float* __restrict__ Wor, const float* __restrict__ Woi,
    float* __restrict__ out, float* __restrict__ ws)
{
    __shared__ unsigned WL[KTOT * NC];   // bf16 pair (real lo, imag hi), 16000 B
    __shared__ float fbuf[G * NC * 2 * NW];  // [b][c][ri][w], 1280 f
    __shared__ float WnlS[NC * 60];          // 960 f
    __shared__ float WoS[2 * 160];           // 320 f
    __shared__ float WcS[4];
    __shared__ float crS[G * 160];           // 640 f
    __shared__ float ciS[G * 160];           // 640 f
    __shared__ float red[G * NC], redq[G * NC];

    const int tid = threadIdx.x;
    const int b   = tid >> 6;          // 0..3 (= wave index)
    const int ks  = (tid >> 4) & 3;    // 0..3
    const int c   = tid & 15;          // 0..15
    const int b0  = blockIdx.x * G;
    const int k0  = ks ? (ks * 60 + 10) : 0;   // 0,70,130,190

    // x[b, n, c, ri]: float2 at element offset n*16 + c (in float2 units)
    const float2* xp = (const float2*)(x + (size_t)(b0 + b) * 8192) + c;

    // ---- issue prologue loads BEFORE staging (overlap with LDS fills) ----
    float2 bA[10], bB[10];
    float accr[10], acci[10];
    #pragma unroll
    for (int j = 0; j < 10; ++j) bA[j] = xp[(k0 + j) * 16];
    #pragma unroll
    for (int j = 0; j < 10; ++j) bB[j] = xp[(k0 + 10 + j) * 16];
    #pragma unroll
    for (int w = 0; w < 10; ++w) { accr[w] = 0.f; acci[w] = 0.f; }

    // ---- stage weights ----
    for (int idx = tid; idx < KTOT * NC; idx += 256) {
        int k = idx >> 4, cc = idx & 15;
        unsigned p = 0;
        if (k < WIN) {
            unsigned r = bf16rne(Wr[cc * WIN + k]);
            unsigned i = bf16rne(Wi[cc * WIN + k]);
            p = r | (i << 16);
        }
        WL[idx] = p;
    }
    for (int idx = tid; idx < NC * 60; idx += 256) WnlS[idx] = Wnl[idx];
    if (tid < 160) { WoS[tid] = Wor[tid]; WoS[160 + tid] = Woi[tid]; }
    if (tid < 4) WcS[tid] = Wc[tid];
    __syncthreads();

    // ---- phase 1: sliding dot products, 2-chunk-lookahead double buffer ----
    CHUNK(k0 +  0, k0 + 20, bA, bB, true)
    CHUNK(k0 + 10, k0 + 30, bB, bA, true)
    CHUNK(k0 + 20, k0 + 40, bA, bB, true)
    CHUNK(k0 + 30, k0 + 50, bB, bA, true)
    CHUNK(k0 + 40, k0 + 60, bA, bB, true)
    CHUNK(k0 + 50, k0 + 70, bB, bA, (ks == 0))   // data chunk 7 only needed by ks0
    if (ks == 0) {
        CHUNK(60, 0, bA, bB, false)              // 7th compute chunk, taps 60..69
    }

    // ---- reduce over ks within wave (lanes: ks*16+c) ----
    #pragma unroll
    for (int w = 0; w < 10; ++w) {
        accr[w] += __shfl_down(accr[w], 32);
        accr[w] += __shfl_down(accr[w], 16);
        acci[w] += __shfl_down(acci[w], 32);
        acci[w] += __shfl_down(acci[w], 16);
    }
    if (ks == 0) {
        #pragma unroll
        for (int w = 0; w < 10; ++w) {
            float fr = accr[w], fi = acci[w];
            float amp = fr * fr + fi * fi;
            fbuf[(b * NC + c) * 20 + w]      = amp * fr;
            fbuf[(b * NC + c) * 20 + 10 + w] = amp * fi;
        }
    }
    __syncthreads();

    // ---- phase 3: neighbor einsum + coeff + output-window weights ----
    for (int idx = tid; idx < G * 160; idx += 256) {
        int bb = idx / 160; int r = idx - bb * 160;
        int cc = r / NW;    int w = r - cc * NW;
        const float* f3 = fbuf + bb * 320;
        const float* wn = WnlS + cc * 60;
        float s0 = 0.f, s1 = 0.f;
        #pragma unroll
        for (int j = 0; j < NC; ++j) {
            if (j != cc) {
                int jj = (j > cc) ? (j - 1) : j;
                float f3r = f3[j * 20 + w];
                float f3i = f3[j * 20 + 10 + w];
                s0 += f3r * wn[jj]      + f3i * wn[15 + jj];
                s1 += f3r * wn[30 + jj] + f3i * wn[45 + jj];
            }
        }
        float p0 = s0 * WcS[0] + s1 * WcS[1];
        float p1 = s0 * WcS[2] + s1 * WcS[3];
        crS[idx] = p0 * WoS[cc * NW + w];
        ciS[idx] = p1 * WoS[160 + cc * NW + w];
    }
    __syncthreads();

    // ---- phase 4: sum over w, write out + BN partials ----
    if (tid < G * NC) {
        int bb = tid >> 4; int cc = tid & 15;
        float orr = 0.f, oii = 0.f;
        #pragma unroll
        for (int w = 0; w < NW; ++w) {
            orr += crS[bb * 160 + cc * NW + w];
            oii += ciS[bb * 160 + cc * NW + w];
        }
        size_t o = ((size_t)(b0 + bb) * NC + cc) * 2;
        out[o]     = orr;
        out[o + 1] = oii;
        red[tid]  = orr + oii;
        redq[tid] = orr * orr + oii * oii;
    }
    __syncthreads();
    if (tid < NC) {
        float s = 0.f, q = 0.f;
        #pragma unroll
        for (int bb = 0; bb < G; ++bb) { s += red[bb * 16 + tid]; q += redq[bb * 16 + tid]; }
        ws[(tid * NBLK + blockIdx.x) * 2]     = s;
        ws[(tid * NBLK + blockIdx.x) * 2 + 1] = q;
    }
}

// ---------------- Kernel 2: reduce partials -> per-channel scale/shift ----------------
__global__ __launch_bounds__(256) void k_bnstat(
    const float* __restrict__ ws_in, float* __restrict__ ws_ab,
    const float* __restrict__ gamma, const float* __restrict__ beta)
{
    const int cch = blockIdx.x;
    const int tid = threadIdx.x;
    float s = 0.f, q = 0.f;
    for (int i = tid; i < NBLK; i += 256) {
        s += ws_in[(cch * NBLK + i) * 2];
        q += ws_in[(cch * NBLK + i) * 2 + 1];
    }
    #pragma unroll
    for (int off = 32; off; off >>= 1) {
        s += __shfl_down(s, off, 64);
        q += __shfl_down(q, off, 64);
    }
    __shared__ float rs[4], rq[4];
    const int wv = tid >> 6;
    if ((tid & 63) == 0) { rs[wv] = s; rq[wv] = q; }
    __syncthreads();
    if (tid == 0) {
        s = rs[0] + rs[1] + rs[2] + rs[3];
        q = rq[0] + rq[1] + rq[2] + rq[3];
        const float inv_n = 1.f / (BTOT * 2.f);
        float mu  = s * inv_n;
        float var = q * inv_n - mu * mu;
        float sc  = gamma[cch] * rsqrtf(var + 1e-5f);
        ws_ab[cch]      = sc;
        ws_ab[16 + cch] = beta[cch] - mu * sc;
    }
}

// ---------------- Kernel 3: apply BN affine in place ----------------
__global__ __launch_bounds__(256) void k_bnapply(
    float* __restrict__ out, const float* __restrict__ ws_ab)
{
    __shared__ float A[16], Bb[16];
    const int tid = threadIdx.x;
    if (tid < 16) { A[tid] = ws_ab[tid]; Bb[tid] = ws_ab[16 + tid]; }
    __syncthreads();
    int idx = blockIdx.x * 256 + tid;
    if (idx < BTOT * NC * 2) {
        int cch = (idx >> 1) & 15;
        out[idx] = out[idx] * A[cch] + Bb[cch];
    }
}

extern "C" void kernel_launch(void* const* d_in, const int* in_sizes, int n_in,
                              void* d_out, int out_size, void* d_ws, size_t ws_size,
                              hipStream_t stream)
{
    const float* x    = (const float*)d_in[0];
    const float* Wr   = (const float*)d_in[1];
    const float* Wi   = (const float*)d_in[2];
    const float* Wnl  = (const float*)d_in[3];
    const float* Wc   = (const float*)d_in[4];
    const float* Wor  = (const float*)d_in[5];
    const float* Woi  = (const float*)d_in[6];
    const float* gam  = (const float*)d_in[7];
    const float* bet  = (const float*)d_in[8];
    float* out = (float*)d_out;
    float* ws  = (float*)d_ws;
    float* ws_ab = ws + NC * NBLK * 2;   // 32768 floats of partials, then 32 floats scale/shift

    k_main<<<NBLK, 256, 0, stream>>>(x, Wr, Wi, Wnl, Wc, Wor, Woi, out, ws);
    k_bnstat<<<NC, 256, 0, stream>>>(ws, ws_ab, gam, bet);
    k_bnapply<<<(BTOT * NC * 2 + 255) / 256, 256, 0, stream>>>(out, ws_ab);
}

// Round 3
// 55.028 us; speedup vs baseline: 1.5473x; 1.5473x over previous
//
#include <hip/hip_runtime.h>

#define BTOT 4096
#define G 8
#define NC 16
#define WIN 247
#define WST 251
#define NBLK (BTOT / G)   // 512

typedef const __attribute__((address_space(1))) void* gas_t;
typedef __attribute__((address_space(3))) void* las_t;
#define GLD16(g, l) __builtin_amdgcn_global_load_lds((gas_t)(g), (las_t)(l), 16, 0, 0)

// One conv tap. All register indices compile-time literals.
#define TAP(JJ, WOFF, DO_LOAD, NLOC)                                   \
    { float wvv = Wp[(WOFF)];                                          \
      _Pragma("unroll")                                                \
      for (int w = 0; w < 10; ++w)                                     \
          acc[w] = fmaf(x16[((JJ) + w + 6) & 15], wvv, acc[w]);        \
      if (DO_LOAD) x16[(JJ) & 15] = xb[(NLOC) * 32]; }

#define TAP16                                                          \
    TAP(0,0,1,0)   TAP(1,1,1,1)   TAP(2,2,1,2)   TAP(3,3,1,3)          \
    TAP(4,4,1,4)   TAP(5,5,1,5)   TAP(6,6,1,6)   TAP(7,7,1,7)          \
    TAP(8,8,1,8)   TAP(9,9,1,9)   TAP(10,10,1,10) TAP(11,11,1,11)      \
    TAP(12,12,1,12) TAP(13,13,1,13) TAP(14,14,1,14) TAP(15,15,1,15)

__global__ __launch_bounds__(256) void k_main(
    const float* __restrict__ x,
    const float* __restrict__ Wr, const float* __restrict__ Wi,
    const float* __restrict__ Wnl, const float* __restrict__ Wc,
    const float* __restrict__ Wor, const float* __restrict__ Woi,
    float* __restrict__ out, float* __restrict__ ws)
{
    __shared__ float xbuf[3 * 4096];            // 49152 B, triple buffer [bi][b][16][32]
    __shared__ float Wlds[2 * NC * WST];        // 32128 B, [ri][c][k] stride 251 (odd)

    const int tid   = threadIdx.x;
    const int lane  = tid & 63;
    const int wv    = tid >> 6;
    const int b_loc = tid >> 5;                 // 0..7
    const int cri   = tid & 31;
    const int ri    = cri & 1;
    const int c     = cri >> 1;
    const int b0    = blockIdx.x * G;

    // ---- stage conv weights (fp32), zero-pad k in [247,250) ----
    for (int idx = tid; idx < 2 * NC * 250; idx += 256) {
        int rr  = idx / (NC * 250);
        int rem = idx - rr * (NC * 250);
        int cc  = rem / 250;
        int k   = rem - cc * 250;
        float v = 0.f;
        if (k < WIN) v = rr ? Wi[cc * WIN + k] : Wr[cc * WIN + k];
        Wlds[rr * (NC * WST) + cc * WST + k] = v;
    }
    __syncthreads();   // W staged & visible; vmcnt drained -> clean count baseline

    // staging: wave wv copies b = 2wv, 2wv+1; 2 x 1KB calls per b
    auto ISSUE = [&](int t, int bi) {
        int n0 = t * 16;
        #pragma unroll
        for (int i = 0; i < 4; ++i) {
            int bl   = wv * 2 + (i >> 1);
            int half = i & 1;
            const float* g = x + (size_t)(b0 + bl) * 8192 + (n0 + half * 8) * 32 + lane * 4;
            float* l = xbuf + bi * 4096 + bl * 512 + half * 256;
            GLD16(g, l);
        }
    };

    float x16[16], acc[10];
    #pragma unroll
    for (int w = 0; w < 10; ++w) acc[w] = 0.f;

    const float* Wp0 = Wlds + ri * (NC * WST) + c * WST;

    ISSUE(0, 0);
    ISSUE(1, 1);

    // ---- iter 0: taps k=0..5 ----
    asm volatile("s_waitcnt vmcnt(4)\n\ts_barrier" ::: "memory");
    ISSUE(2, 2);
    {
        const float* xb = xbuf + b_loc * 512 + cri;
        #pragma unroll
        for (int n = 0; n < 10; ++n) x16[n] = xb[n * 32];
        const float* Wp = Wp0;
        TAP(10, 0, 1, 10) TAP(11, 1, 1, 11) TAP(12, 2, 1, 12)
        TAP(13, 3, 1, 13) TAP(14, 4, 1, 14) TAP(15, 5, 1, 15)
    }

    // ---- iters 1..14: taps k = 16t-10 .. 16t+5 ----
    int bi = 1, bin2 = 0;   // bi = t%3, bin2 = (t+2)%3
    #pragma unroll 1
    for (int t = 1; t <= 14; ++t) {
        asm volatile("s_waitcnt vmcnt(4)\n\ts_barrier" ::: "memory");
        if (t <= 13) ISSUE(t + 2, bin2);
        const float* xb = xbuf + bi * 4096 + b_loc * 512 + cri;
        const float* Wp = Wp0 + 16 * t - 10;
        TAP16
        bi   = (bi   == 2) ? 0 : bi   + 1;
        bin2 = (bin2 == 2) ? 0 : bin2 + 1;
    }

    // ---- iter 15: taps k=230..245 ----
    asm volatile("s_waitcnt vmcnt(0)\n\ts_barrier" ::: "memory");
    {
        const float* xb = xbuf + bi * 4096 + b_loc * 512 + cri;
        const float* Wp = Wp0 + 230;
        TAP16
    }
    // ---- tail tap k=246 (no load) ----
    {
        const float* Wp = Wp0 + 246;
        const float* xb = xbuf;  // unused
        TAP(0, 0, 0, 0)
    }

    __syncthreads();   // conv reads done -> alias region reuse is safe

    // ---- phase 2: amp nonlinearity via partner-lane shuffle ----
    float* fbuf = xbuf;                 // [b][c][ri][w] : b*320 + cri*10 + w (2560 f)
    float* WnlS = xbuf + 2560;          // 960 f
    float* WoS  = xbuf + 3520;          // 320 f
    float* WcS  = xbuf + 3840;          // 4 f
    float* crS  = xbuf + 3848;          // 1280 f
    float* ciS  = xbuf + 5128;          // 1280 f
    float* red  = xbuf + 6408;          // 128 f
    float* redq = xbuf + 6536;          // 128 f

    #pragma unroll
    for (int w = 0; w < 10; ++w) {
        float other = __shfl_xor(acc[w], 1);
        float amp   = acc[w] * acc[w] + other * other;
        fbuf[b_loc * 320 + cri * 10 + w] = amp * acc[w];
    }
    for (int idx = tid; idx < NC * 60; idx += 256) WnlS[idx] = Wnl[idx];
    if (tid < 160) { WoS[tid] = Wor[tid]; WoS[160 + tid] = Woi[tid]; }
    if (tid < 4) WcS[tid] = Wc[tid];
    __syncthreads();

    // ---- phase 3: neighbor einsum + coeff + output-window weights ----
    for (int idx = tid; idx < G * 160; idx += 256) {
        int bb = idx / 160; int r = idx - bb * 160;
        int cc = r / 10;    int w = r - cc * 10;
        const float* f3 = fbuf + bb * 320;
        const float* wn = WnlS + cc * 60;
        float s0 = 0.f, s1 = 0.f;
        #pragma unroll
        for (int j = 0; j < NC; ++j) {
            if (j != cc) {
                int jj = (j > cc) ? (j - 1) : j;
                float f3r = f3[j * 20 + w];
                float f3i = f3[j * 20 + 10 + w];
                s0 += f3r * wn[jj]      + f3i * wn[15 + jj];
                s1 += f3r * wn[30 + jj] + f3i * wn[45 + jj];
            }
        }
        float p0 = s0 * WcS[0] + s1 * WcS[1];
        float p1 = s0 * WcS[2] + s1 * WcS[3];
        crS[idx] = p0 * WoS[cc * 10 + w];
        ciS[idx] = p1 * WoS[160 + cc * 10 + w];
    }
    __syncthreads();

    // ---- phase 4: sum over w, write out + BN partials ----
    if (tid < G * NC) {
        int bb = tid >> 4; int cc = tid & 15;
        float orr = 0.f, oii = 0.f;
        #pragma unroll
        for (int w = 0; w < 10; ++w) {
            orr += crS[bb * 160 + cc * 10 + w];
            oii += ciS[bb * 160 + cc * 10 + w];
        }
        size_t o = ((size_t)(b0 + bb) * NC + cc) * 2;
        out[o]     = orr;
        out[o + 1] = oii;
        red[tid]  = orr + oii;
        redq[tid] = orr * orr + oii * oii;
    }
    __syncthreads();
    if (tid < NC) {
        float s = 0.f, q = 0.f;
        #pragma unroll
        for (int bb = 0; bb < G; ++bb) { s += red[bb * 16 + tid]; q += redq[bb * 16 + tid]; }
        ws[(tid * NBLK + blockIdx.x) * 2]     = s;
        ws[(tid * NBLK + blockIdx.x) * 2 + 1] = q;
    }
}

// ---------------- Kernel 2: reduce partials -> per-channel scale/shift ----------------
__global__ __launch_bounds__(256) void k_bnstat(
    const float* __restrict__ ws_in, float* __restrict__ ws_ab,
    const float* __restrict__ gamma, const float* __restrict__ beta)
{
    const int cch = blockIdx.x;
    const int tid = threadIdx.x;
    float s = 0.f, q = 0.f;
    for (int i = tid; i < NBLK; i += 256) {
        s += ws_in[(cch * NBLK + i) * 2];
        q += ws_in[(cch * NBLK + i) * 2 + 1];
    }
    #pragma unroll
    for (int off = 32; off; off >>= 1) {
        s += __shfl_down(s, off, 64);
        q += __shfl_down(q, off, 64);
    }
    __shared__ float rs[4], rq[4];
    const int wv = tid >> 6;
    if ((tid & 63) == 0) { rs[wv] = s; rq[wv] = q; }
    __syncthreads();
    if (tid == 0) {
        s = rs[0] + rs[1] + rs[2] + rs[3];
        q = rq[0] + rq[1] + rq[2] + rq[3];
        const float inv_n = 1.f / (BTOT * 2.f);
        float mu  = s * inv_n;
        float var = q * inv_n - mu * mu;
        float sc  = gamma[cch] * rsqrtf(var + 1e-5f);
        ws_ab[cch]      = sc;
        ws_ab[16 + cch] = beta[cch] - mu * sc;
    }
}

// ---------------- Kernel 3: apply BN affine in place ----------------
__global__ __launch_bounds__(256) void k_bnapply(
    float* __restrict__ out, const float* __restrict__ ws_ab)
{
    __shared__ float A[16], Bb[16];
    const int tid = threadIdx.x;
    if (tid < 16) { A[tid] = ws_ab[tid]; Bb[tid] = ws_ab[16 + tid]; }
    __syncthreads();
    int idx = blockIdx.x * 256 + tid;
    if (idx < BTOT * NC * 2) {
        int cch = (idx >> 1) & 15;
        out[idx] = out[idx] * A[cch] + Bb[cch];
    }
}

extern "C" void kernel_launch(void* const* d_in, const int* in_sizes, int n_in,
                              void* d_out, int out_size, void* d_ws, size_t ws_size,
                              hipStream_t stream)
{
    const float* x    = (const float*)d_in[0];
    const float* Wr   = (const float*)d_in[1];
    const float* Wi   = (const float*)d_in[2];
    const float* Wnl  = (const float*)d_in[3];
    const float* Wc   = (const float*)d_in[4];
    const float* Wor  = (const float*)d_in[5];
    const float* Woi  = (const float*)d_in[6];
    const float* gam  = (const float*)d_in[7];
    const float* bet  = (const float*)d_in[8];
    float* out = (float*)d_out;
    float* ws  = (float*)d_ws;
    float* ws_ab = ws + NC * NBLK * 2;   // 16384 floats of partials, then 32 floats scale/shift

    k_main<<<NBLK, 256, 0, stream>>>(x, Wr, Wi, Wnl, Wc, Wor, Woi, out, ws);
    k_bnstat<<<NC, 256, 0, stream>>>(ws, ws_ab, gam, bet);
    k_bnapply<<<(BTOT * NC * 2 + 255) / 256, 256, 0, stream>>>(out, ws_ab);
}